// Round 6
// baseline (413.538 us; speedup 1.0000x reference)
//
#include <hip/hip_runtime.h>
#include <math.h>

#define H_FM 200
#define W_FM 304
#define C_FM 256
#define NPIX (H_FM * W_FM)            // 60800
#define PH 7
#define NPOS 49                        // 7*7
#define SLABS 16
#define SLAB_C 16                      // channels per slab
#define SLAB_ELEMS (NPIX * SLAB_C)     // 3.89 MB contiguous -> dense in one XCD L2

typedef float floatx4 __attribute__((ext_vector_type(4)));

// ---------------------------------------------------------------------------
// Repack [NPIX,256] -> 16 contiguous slabs [NPIX,16] via LDS transpose.
// R5's direct repack was ~100+ us: its stores fragmented into 16x64B segments
// per wave instruction. Here both global phases are per-instruction dense:
//   load : 8 iters x 4 KB fully coalesced (wave reads 1 KB contiguous)
//   store: 8 iters, each wave writes 1 KB contiguous within one slab region
// LDS = 16 slabs x (32 px x 16 ch + 4 pad) floats = 33 KB. ds_*_b128 runs at
// its structural 8-cyc floor (64 lanes x 16B over 32 banks) either way.
#define RP_PIX 32
#define RP_STRIDE (RP_PIX * SLAB_C + 4)   // 516 floats per slab region in LDS

__global__ __launch_bounds__(256) void repack_kernel(
    const float* __restrict__ fm,      // [NPIX, 256]
    float*       __restrict__ slabbed) // [16][NPIX][16]
{
    __shared__ float lds[SLABS * RP_STRIDE];
    const int t  = threadIdx.x;
    const int P0 = blockIdx.x * RP_PIX;

    #pragma unroll
    for (int i = 0; i < 8; ++i) {
        const int flat = i * 256 + t;       // float4 index within the 32-px tile
        const int p    = flat >> 6;         // local pixel (wave-uniform)
        const int c4   = flat & 63;         // channel quad 0..63
        const int s    = c4 >> 2;           // slab
        const int cq   = c4 & 3;            // quad within slab
        const float4 v = *(const float4*)(fm + ((size_t)(P0 + p) * C_FM + c4 * 4));
        *(float4*)(&lds[s * RP_STRIDE + p * SLAB_C + cq * 4]) = v;
    }
    __syncthreads();
    #pragma unroll
    for (int i = 0; i < 8; ++i) {
        const int flat = i * 256 + t;       // float4 index in output order
        const int s    = flat >> 7;         // 128 float4 per slab chunk
        const int off  = flat & 127;
        const float4 v = *(const float4*)(&lds[s * RP_STRIDE + off * 4]);
        *(float4*)(slabbed + ((size_t)s * SLAB_ELEMS + (size_t)P0 * SLAB_C + off * 4)) = v;
    }
}

// ---------------------------------------------------------------------------
// Main kernel: block = 256 thr = 4 waves; wave w handles ROI n = ngrp*4+w for
// ONE slab (all 4 waves same slab -> one 3.9 MB slab per XCD L2, pinned via
// xcd = bid & 7; XCD x streams slab x for all N ROIs, then slab x+8).
// Lane = output position p (49 of 64 active). Each lane:
//   - computes the 2 y-coord sets + 2 x-coord sets ONCE (covers all 4 samples)
//   - serially loops 4 samples x 4 channel-quads: 4 neighbor float4 loads,
//     reference-order lerp, running max -> NO cross-lane shuffles
//   - stores its 64 B output run (4 nontemporal float4s)
// vs R5: ~2x fewer VALU instr per output, zero ds_swizzle.
template <bool SLABBED>
__global__ __launch_bounds__(256) void roi_pool_kernel(
    const float* __restrict__ fmbase,      // SLABBED ? [16][NPIX][16] : [NPIX,256]
    const float* __restrict__ proposals,   // [N,4] (x1,y1,x2,y2) image coords
    const int*   __restrict__ image_shape, // [2] (H_img, W_img)
    float*       __restrict__ out,         // [N, 7, 7, 256]
    int N, int gpp)                        // gpp = ceil(N/4)
{
    const int bid   = blockIdx.x;
    const int xcd   = bid & 7;
    const int g     = bid >> 3;            // 0 .. 2*gpp-1
    const int phase = (g >= gpp) ? 1 : 0;
    const int ngrp  = g - phase * gpp;
    const int wave  = threadIdx.x >> 6;
    const int lane  = threadIdx.x & 63;
    const int n     = ngrp * 4 + wave;
    if (n >= N) return;
    const int slab  = phase * 8 + xcd;
    const int c0    = slab * SLAB_C;

    const int p = lane;
    if (p >= NPOS) return;
    const int py = p / PH;
    const int px = p - py * PH;

    const float himg = (float)image_shape[0];
    const float wimg = (float)image_shape[1];
    const float4 box = *(const float4*)(proposals + (size_t)n * 4);
    const float bx1 = box.x / wimg, by1 = box.y / himg;
    const float bx2 = box.z / wimg, by2 = box.w / himg;

    const float Hm1 = (float)(H_FM - 1);
    const float Wm1 = (float)(W_FM - 1);
    // Matches reference: ys = y1*(H-1) + idx * ((y2-y1)*(H-1)/(crop-1))
    const float ybase = by1 * Hm1;
    const float xbase = bx1 * Wm1;
    const float ystep = (by2 - by1) * Hm1 / 13.0f;
    const float xstep = (bx2 - bx1) * Wm1 / 13.0f;

    // coord sets, computed once per lane (a/b = sub-sample offsets)
    float ly[2], lx[2];
    int   rA[2], rB[2], cA[2], cB[2];
    bool  vy[2], vx[2];
    #pragma unroll
    for (int a = 0; a < 2; ++a) {
        const float ysv = ybase + (float)(2 * py + a) * ystep;
        const float y0f = floorf(ysv);
        ly[a] = ysv - y0f;
        int y0 = (int)y0f;
        y0 = min(max(y0, 0), H_FM - 1);
        rA[a] = y0 * W_FM;
        rB[a] = min(y0 + 1, H_FM - 1) * W_FM;
        vy[a] = (ysv >= 0.0f) && (ysv <= Hm1);
    }
    #pragma unroll
    for (int b = 0; b < 2; ++b) {
        const float xsv = xbase + (float)(2 * px + b) * xstep;
        const float x0f = floorf(xsv);
        lx[b] = xsv - x0f;
        int x0 = (int)x0f;
        x0 = min(max(x0, 0), W_FM - 1);
        cA[b] = x0;
        cB[b] = min(x0 + 1, W_FM - 1);
        vx[b] = (xsv >= 0.0f) && (xsv <= Wm1);
    }

    const float* fmq = SLABBED ? fmbase + (size_t)slab * SLAB_ELEMS
                               : fmbase + c0;
    const int PIX = SLABBED ? SLAB_C : C_FM;

    float4 acc[4];
    #pragma unroll
    for (int q = 0; q < 4; ++q)
        acc[q] = make_float4(-INFINITY, -INFINITY, -INFINITY, -INFINITY);

    #pragma unroll
    for (int s = 0; s < 4; ++s) {
        const int a = s >> 1, b = s & 1;
        const float lyv = ly[a], lxv = lx[b];
        const bool valid = vy[a] && vx[b];
        const size_t o00 = (size_t)(rA[a] + cA[b]) * PIX;
        const size_t o01 = (size_t)(rA[a] + cB[b]) * PIX;
        const size_t o10 = (size_t)(rB[a] + cA[b]) * PIX;
        const size_t o11 = (size_t)(rB[a] + cB[b]) * PIX;

        #pragma unroll
        for (int q = 0; q < 4; ++q) {
            float4 val = make_float4(0.0f, 0.0f, 0.0f, 0.0f);
            if (valid) {
                const float4 v00 = *(const float4*)(fmq + o00 + q * 4);
                const float4 v01 = *(const float4*)(fmq + o01 + q * 4);
                const float4 v10 = *(const float4*)(fmq + o10 + q * 4);
                const float4 v11 = *(const float4*)(fmq + o11 + q * 4);
                // reference op order: top = v00 + (v01-v00)*lx, etc.
                float tx, ty, tz, tw, bx, by, bz, bw;
                tx = v00.x + (v01.x - v00.x) * lxv;
                ty = v00.y + (v01.y - v00.y) * lxv;
                tz = v00.z + (v01.z - v00.z) * lxv;
                tw = v00.w + (v01.w - v00.w) * lxv;
                bx = v10.x + (v11.x - v10.x) * lxv;
                by = v10.y + (v11.y - v10.y) * lxv;
                bz = v10.z + (v11.z - v10.z) * lxv;
                bw = v10.w + (v11.w - v10.w) * lxv;
                val.x = tx + (bx - tx) * lyv;
                val.y = ty + (by - ty) * lyv;
                val.z = tz + (bz - tz) * lyv;
                val.w = tw + (bw - tw) * lyv;
            }
            acc[q].x = fmaxf(acc[q].x, val.x);
            acc[q].y = fmaxf(acc[q].y, val.y);
            acc[q].z = fmaxf(acc[q].z, val.z);
            acc[q].w = fmaxf(acc[q].w, val.w);
        }
    }

    float* op = out + ((size_t)n * NPOS + p) * C_FM + c0;
    #pragma unroll
    for (int q = 0; q < 4; ++q) {
        floatx4 v;
        v.x = acc[q].x; v.y = acc[q].y; v.z = acc[q].z; v.w = acc[q].w;
        // non-temporal: keep the 98 MB output stream from evicting the slab
        __builtin_nontemporal_store(v, (floatx4*)(op + q * 4));
    }
}

extern "C" void kernel_launch(void* const* d_in, const int* in_sizes, int n_in,
                              void* d_out, int out_size, void* d_ws, size_t ws_size,
                              hipStream_t stream) {
    const float* fm        = (const float*)d_in[0];  // [1,200,304,256] f32
    const float* proposals = (const float*)d_in[1];  // [N,4] f32
    const int*   imshape   = (const int*)d_in[2];    // [2] i32
    float* out = (float*)d_out;                      // [N,7,7,256] f32

    const int N   = in_sizes[1] / 4;                 // 2000
    const int gpp = (N + 3) / 4;                     // ROI groups per phase
    const size_t needed = (size_t)SLABS * SLAB_ELEMS * sizeof(float); // 62.3 MB

    if (ws_size >= needed) {
        repack_kernel<<<NPIX / RP_PIX, 256, 0, stream>>>(fm, (float*)d_ws);
        roi_pool_kernel<true><<<16 * gpp, 256, 0, stream>>>(
            (const float*)d_ws, proposals, imshape, out, N, gpp);
    } else {
        roi_pool_kernel<false><<<16 * gpp, 256, 0, stream>>>(
            fm, proposals, imshape, out, N, gpp);
    }
}